// Round 8
// baseline (124.849 us; speedup 1.0000x reference)
//
#include <hip/hip_runtime.h>
#include <math.h>

// fab_penalty_ls_curve: curvature penalty over mirrored level-set field.
// R8: R6(global/L1) and R7(LDS) both plateaued at 45us, VALUBusy~50% -> not
// memory-pipe-bound; limiter is ~105 VALU ops/pt + latency at low ILP.
// This round: (1) unscaled-diff math: all 1/d powers factored analytically,
// SC dropped in interior (exact zeros never occur in continuous data; 2%
// threshold), trans ops 3->2 (rsqrt reused for sqrt and ^-1.5): ~41 ops/pt.
// (2) 2 adjacent cols/thread from the LDS tile via float2: 11 conflict-free
// ds_read_b64 per 2 points (5.5/pt vs 13), reads batched (R2/R5 MLP lesson).
// (3) ROWS_PER=8, tile 516x12=24.8KB -> ~5-6 blocks/CU for latency hiding.
// Plain partial stores (device-scope atomic finish = R2/R3 3x regression).
// Mirror-half trick: compute left half only, x2 (verified absmax 0.0).

#define BLOCK_X 256
#define ROWS_PER 8
#define TILE_COLS (2 * BLOCK_X + 4)   // 516
#define TILE_F2   (TILE_COLS / 2)     // 258
#define TILE_H    (ROWS_PER + 4)      // 12

__device__ __forceinline__ float curve_pt(
    float nn, float nw, float n, float ne,
    float ww, float w, float c, float e, float ee,
    float sw, float s, float se, float ss,
    float rd2, float two_d)
{
    const float pi_d = 3.14159265358979323846f / 1.1f;
    // unscaled central differences (interior): ex = u*rd2, exx = U*rd2^2, ...
    const float u  = s - n;
    const float v  = e - w;
    const float U  = fmaf(-2.0f, c, ss + nn);
    const float V  = fmaf(-2.0f, c, ee + ww);
    const float X2 = 2.0f * ((se - ne) - (sw - nw));
    const float u2 = u * u, v2 = v * v, uv = u * v;
    float W = u2 * V;
    W = fmaf(v2, U, W);
    W = fmaf(-uv, X2, W);                 // W = u^2 V + v^2 U - 2 u v X
    const float S  = u2 + v2;
    const float rsq = __builtin_amdgcn_rsqf(S);   // S^-0.5
    const float r3  = (rsq * rsq) * rsq;          // S^-1.5
    const float kk  = fabsf(W) * r3;              // |k| / rd2
    const float ae  = fabsf(c);
    const float rc  = __builtin_amdgcn_rcpf(ae);
    const float sq  = S * rsq;                    // sqrt(S)
    const float q   = (rd2 * sq) * rc;            // ev/|eps|  (>0)
    const float iq  = (ae * rsq) * two_d;         // 1/q
    const bool  big = q > 1.0f;
    const float t   = big ? iq : q;
    const float s2  = t * t;
    float p = fmaf(s2, -0.01172120f, 0.05265332f);
    p = fmaf(s2, p, -0.11643287f);
    p = fmaf(s2, p,  0.19354346f);
    p = fmaf(s2, p, -0.33262347f);
    p = fmaf(s2, p,  0.99997726f);
    float at = p * t;
    at = big ? (1.57079632679f - at) : at;        // atan(ev/|eps|)
    const float cc = fmaf(kk * rd2, at, -pi_d);   // |k|*atan - pi_d
    return fmaxf(cc, 0.0f);    // fmax(NaN,0)=0 -> nansum semantics (S==0 etc.)
}

// Generic path: row clamps (one-sided diffs) and column clamp/mirror.
// Used for y-edge blocks and the j=0,1 lanes of the x=0 block.
__device__ float generic_rows(const float* __restrict__ eps, int Hn, int Wn,
                              int i0, int j, float rd)
{
    const float rd2 = 0.5f * rd;
    const float SC = 1e-12f;
    const float FLOORV = (float)(1e-32 / 6.0);
    const float pi_d = 3.14159265358979323846f / 1.1f;

    const int jm  = (j > 0) ? j - 1 : 0;
    const int jmm = (j > 1) ? j - 2 : 0;
    const int jp = j + 1, jpp = j + 2;
    const int cjp  = (jp  < Wn) ? jp  : (2 * Wn - 1 - jp);   // mirror seam
    const int cjpp = (jpp < Wn) ? jpp : (2 * Wn - 1 - jpp);
    const float syj = (j == 0)  ? rd : rd2;
    const float sym = (jm == 0) ? rd : rd2;
    const float syp = rd2;   // jp never a boundary of the 2W virtual grid

    float acc = 0.0f;
    for (int r = 0; r < ROWS_PER; ++r) {
        const int i = i0 + r;
        if (i >= Hn) break;
        const int im  = (i > 0) ? i - 1 : 0;
        const int ip  = (i < Hn - 1) ? i + 1 : Hn - 1;
        const int imm = (im > 0) ? im - 1 : 0;
        const int ipp = (ip < Hn - 1) ? ip + 1 : Hn - 1;
        const float sxi = (i == 0 || i == Hn - 1) ? rd : rd2;
        const float sxm = (im == 0) ? rd : rd2;
        const float sxp = (ip == Hn - 1) ? rd : rd2;

        const float* rowc  = eps + (size_t)i   * (size_t)Wn;
        const float* rown  = eps + (size_t)im  * (size_t)Wn;
        const float* rows_ = eps + (size_t)ip  * (size_t)Wn;
        const float* rownn = eps + (size_t)imm * (size_t)Wn;
        const float* rowss = eps + (size_t)ipp * (size_t)Wn;

        const float e_c  = rowc[j];
        const float e_n  = rown[j],   e_s  = rows_[j];
        const float e_nn = rownn[j],  e_ss = rowss[j];
        const float e_w  = rowc[jm],  e_e  = rowc[cjp];
        const float e_ww = rowc[jmm], e_ee = rowc[cjpp];
        const float e_nw = rown[jm],  e_ne = rown[cjp];
        const float e_sw = rows_[jm], e_se = rows_[cjp];

        const float ex = fmaf(e_s - e_n, sxi, SC);
        const float ey = fmaf(e_e - e_w, syj, SC);
        float exn = fmaf(e_c - e_nn, sxm, SC);
        float exs = fmaf(e_ss - e_c, sxp, SC);
        if (i == 0)      exn = ex;
        if (i == Hn - 1) exs = ex;
        const float exx = (exs - exn) * sxi;
        float eyw = fmaf(e_c - e_ww, sym, SC);
        const float eye = fmaf(e_ee - e_c, syp, SC);
        if (j == 0) eyw = ey;
        const float eyy = (eye - eyw) * syj;
        const float exy = ((e_se - e_ne) - (e_sw - e_nw)) * (sxi * syj);

        const float t1 = ex * ex;
        const float t2 = ey * ey;
        float num = t1 * eyy;
        num = fmaf(t2, exx, num);
        num = fmaf(-2.0f * (ex * ey), exy, num);

        float ev = __builtin_amdgcn_sqrtf(t1 + t2);
        ev = fmaxf(ev, FLOORV);
        const float rv = __builtin_amdgcn_rcpf(ev);
        const float k  = num * (rv * rv) * rv;
        // atan(ev/e_c) via |.| identity, reusing rv
        const float ae = fabsf(e_c);
        const float rc = __builtin_amdgcn_rcpf(ae);
        const float q  = ev * rc;
        const float iq = ae * rv;
        const bool  big = q > 1.0f;
        const float t  = big ? iq : q;
        const float s2 = t * t;
        float p = fmaf(s2, -0.01172120f, 0.05265332f);
        p = fmaf(s2, p, -0.11643287f);
        p = fmaf(s2, p,  0.19354346f);
        p = fmaf(s2, p, -0.33262347f);
        p = fmaf(s2, p,  0.99997726f);
        float at = p * t;
        at = big ? (1.57079632679f - at) : at;
        const float cc = fabsf(k) * at - pi_d;
        acc += fmaxf(cc, 0.0f);
    }
    return acc;
}

__global__ __launch_bounds__(BLOCK_X, 4) void curve_partial_kernel(
    const float* __restrict__ eps, const float* __restrict__ gs,
    double* __restrict__ partial, int Hn, int Wn)
{
    __shared__ float2 tile2[TILE_H * TILE_F2];   // 24768 B
    const int tx = threadIdx.x;
    const int jb = blockIdx.x * (2 * BLOCK_X);
    const int i0 = blockIdx.y * ROWS_PER;
    const float d  = gs[0];
    const float rd = 1.0f / d;
    const float rd2 = 0.5f * rd;
    const float two_d = 2.0f * d;

    const int p0 = jb + 2 * tx;          // this thread's two columns
    const int p1 = p0 + 1;

    // staged rows i0-2 .. i0+ROWS_PER+1 must all be in-bounds
    const bool row_int = (i0 >= 2) && (i0 + ROWS_PER + 2 <= Hn);

    float accf = 0.0f;
    if (row_int) {
        const float* gbase = eps + (size_t)(i0 - 2) * (size_t)Wn;
        const bool cint = (jb >= 2) && (jb + 2 * BLOCK_X + 2 <= Wn);
        if (cint) {
            // coalesced float2 staging: f2 slot m covers cols jb-2+2m, +1
            const float2* g2 = (const float2*)(gbase + (jb - 2));
            const size_t rs = (size_t)(Wn / 2);
            #pragma unroll
            for (int r = 0; r < TILE_H; ++r)
                tile2[r * TILE_F2 + tx] = g2[(size_t)r * rs + tx];
            if (tx < 2) {
                #pragma unroll
                for (int r = 0; r < TILE_H; ++r)
                    tile2[r * TILE_F2 + BLOCK_X + tx] = g2[(size_t)r * rs + BLOCK_X + tx];
            }
        } else {
            // edge col-block: scalar staging with clamp (left) / mirror (right)
            float* tf = (float*)tile2;
            int c0 = jb - 2 + 2 * tx, c1 = c0 + 1;
            c0 = (c0 < 0) ? 0 : ((c0 >= Wn) ? 2 * Wn - 1 - c0 : c0);
            c1 = (c1 < 0) ? 0 : ((c1 >= Wn) ? 2 * Wn - 1 - c1 : c1);
            #pragma unroll
            for (int r = 0; r < TILE_H; ++r) {
                tf[r * TILE_COLS + 2 * tx]     = gbase[(size_t)r * Wn + c0];
                tf[r * TILE_COLS + 2 * tx + 1] = gbase[(size_t)r * Wn + c1];
            }
            if (tx < 2) {
                int e0 = jb - 2 + 2 * (BLOCK_X + tx), e1 = e0 + 1;
                e0 = (e0 < 0) ? 0 : ((e0 >= Wn) ? 2 * Wn - 1 - e0 : e0);
                e1 = (e1 < 0) ? 0 : ((e1 >= Wn) ? 2 * Wn - 1 - e1 : e1);
                #pragma unroll
                for (int r = 0; r < TILE_H; ++r) {
                    tf[r * TILE_COLS + 2 * (BLOCK_X + tx)]     = gbase[(size_t)r * Wn + e0];
                    tf[r * TILE_COLS + 2 * (BLOCK_X + tx) + 1] = gbase[(size_t)r * Wn + e1];
                }
            }
        }
        __syncthreads();

        if (p0 >= 2 && p1 < Wn) {
            // LDS fast path: 11 conflict-free ds_read_b64 per row-iteration
            // serve 2 points. Mirror staging makes the right seam exact.
            const float2* t2 = tile2;
            const int b = tx;
            #pragma unroll
            for (int r = 0; r < ROWS_PER; ++r) {
                const float2 A  = t2[(r + 0) * TILE_F2 + b + 1];
                const float2 B0 = t2[(r + 1) * TILE_F2 + b    ];
                const float2 B1 = t2[(r + 1) * TILE_F2 + b + 1];
                const float2 B2 = t2[(r + 1) * TILE_F2 + b + 2];
                const float2 C0 = t2[(r + 2) * TILE_F2 + b    ];
                const float2 C1 = t2[(r + 2) * TILE_F2 + b + 1];
                const float2 C2 = t2[(r + 2) * TILE_F2 + b + 2];
                const float2 D0 = t2[(r + 3) * TILE_F2 + b    ];
                const float2 D1 = t2[(r + 3) * TILE_F2 + b + 1];
                const float2 D2 = t2[(r + 3) * TILE_F2 + b + 2];
                const float2 E  = t2[(r + 4) * TILE_F2 + b + 1];
                // point 0: col p0 (tile col 2tx+2)
                accf += curve_pt(A.x, B0.y, B1.x, B1.y,
                                 C0.x, C0.y, C1.x, C1.y, C2.x,
                                 D0.y, D1.x, D1.y, E.x, rd2, two_d);
                // point 1: col p1 (tile col 2tx+3)
                accf += curve_pt(A.y, B1.x, B1.y, B2.x,
                                 C0.y, C1.x, C1.y, C2.x, C2.y,
                                 D1.x, D1.y, D2.x, E.y, rd2, two_d);
            }
        } else {
            // j=0,1 lanes of block x==0 (and any ragged tail)
            if (p0 < Wn) accf += generic_rows(eps, Hn, Wn, i0, p0, rd);
            if (p1 < Wn) accf += generic_rows(eps, Hn, Wn, i0, p1, rd);
        }
    } else {
        if (p0 < Wn) accf += generic_rows(eps, Hn, Wn, i0, p0, rd);
        if (p1 < Wn) accf += generic_rows(eps, Hn, Wn, i0, p1, rd);
    }

    double acc = (double)accf;
    #pragma unroll
    for (int off = 32; off > 0; off >>= 1)
        acc += __shfl_down(acc, off, 64);
    __shared__ double ldsr[BLOCK_X / 64];
    const int lane = tx & 63, wv = tx >> 6;
    if (lane == 0) ldsr[wv] = acc;
    __syncthreads();
    if (tx == 0) {
        // plain store — NO device-scope atomics
        partial[blockIdx.y * gridDim.x + blockIdx.x] =
            ldsr[0] + ldsr[1] + ldsr[2] + ldsr[3];
    }
}

__global__ __launch_bounds__(256) void curve_finish_kernel(
    const double* __restrict__ partial, int n,
    const float* __restrict__ gs, float* __restrict__ out)
{
    const int tx = threadIdx.x;
    double acc = 0.0;
    for (int idx = tx; idx < n; idx += 256) acc += partial[idx];
    #pragma unroll
    for (int off = 32; off > 0; off >>= 1)
        acc += __shfl_down(acc, off, 64);
    __shared__ double lds[4];
    const int lane = tx & 63, wv = tx >> 6;
    if (lane == 0) lds[wv] = acc;
    __syncthreads();
    if (tx == 0) {
        const double d = (double)gs[0];
        // x2 for the mirrored half; x d^2 for grid_size^2 (ALPHA=1)
        out[0] = (float)((lds[0] + lds[1] + lds[2] + lds[3]) * 2.0 * d * d);
    }
}

extern "C" void kernel_launch(void* const* d_in, const int* in_sizes, int n_in,
                              void* d_out, int out_size, void* d_ws, size_t ws_size,
                              hipStream_t stream) {
    const float* eps = (const float*)d_in[0];
    const float* gs  = (const float*)d_in[1];
    float* out = (float*)d_out;

    const int n = in_sizes[0];
    int Wn = (int)(sqrt((double)n) + 0.5);   // 4096 for 4096x4096
    int Hn = n / Wn;

    const int gx = (Wn + 2 * BLOCK_X - 1) / (2 * BLOCK_X);   // 8
    const int gy = (Hn + ROWS_PER - 1) / ROWS_PER;           // 512
    double* partial = (double*)d_ws;   // gx*gy slots, ALL written every launch

    curve_partial_kernel<<<dim3(gx, gy), BLOCK_X, 0, stream>>>(eps, gs, partial, Hn, Wn);
    curve_finish_kernel<<<1, 256, 0, stream>>>(partial, gx * gy, gs, out);
}